// Round 6
// baseline (1470.637 us; speedup 1.0000x reference)
//
#include <hip/hip_runtime.h>
#include <hip/hip_cooperative_groups.h>
#include <stdint.h>

namespace cg = cooperative_groups;

#define N_NODES 50000
#define N_EDGES 625000
#define DIN 256
#define HD 128
#define LN_EPS 1e-5f

#define GEMM_GRID 782      // (N_NODES+63)/64
#define EDGE_GRID 2442     // (N_EDGES+255)/256
#define NODE_GRID 196      // (N_NODES+255)/256
#define FILL_CHUNKS 153    // ceil(625000/4096)
#define MONO_GRID 1536     // 6 blocks/CU x 256 CUs

typedef __attribute__((ext_vector_type(8))) short bvec8;
typedef __attribute__((ext_vector_type(4))) float fvec4;

__device__ inline float bf2f(ushort u){
  union { uint32_t u32; float f; } c; c.u32 = ((uint32_t)u) << 16; return c.f;
}
__device__ inline ushort f2bf(float f){
  union { float f; uint32_t u; } c; c.f = f;
  uint32_t u = c.u;
  return (ushort)((u + 0x7fffu + ((u >> 16) & 1u)) >> 16);
}
__device__ inline float rdany(const void* p, int i, int f32){
  return f32 ? ((const float*)p)[i] : bf2f(((const ushort*)p)[i]);
}

// ================= mono-kernel device pieces (16KB quarter-staged) =================

__device__ void mono_gather(int node, int l16, const ushort* __restrict__ h,
                            const int* __restrict__ rowstart, const int* __restrict__ cnt,
                            const int* __restrict__ esrc, ushort* __restrict__ agg){
  int b   = rowstart[node];
  int deg = cnt[node];
  int e   = b + deg;
  float acc[8];
  #pragma unroll
  for (int j = 0; j < 8; j++) acc[j] = 0.f;
  for (int i = b; i < e; i += 8){
    int idx[8];
    #pragma unroll
    for (int k = 0; k < 8; k++){
      int ee = i + k;
      idx[k] = esrc[ee < e ? ee : e - 1];
    }
    uint4 r[8];
    #pragma unroll
    for (int k = 0; k < 8; k++)
      r[k] = *(const uint4*)(h + (size_t)idx[k] * HD + l16 * 8);
    #pragma unroll
    for (int k = 0; k < 8; k++){
      if (i + k < e){
        const uint32_t* w = (const uint32_t*)&r[k];
        #pragma unroll
        for (int j = 0; j < 4; j++){
          acc[2*j]   += bf2f((ushort)(w[j] & 0xffffu));
          acc[2*j+1] += bf2f((ushort)(w[j] >> 16));
        }
      }
    }
  }
  float scale = (deg > 0) ? 1.f / (float)deg : 0.f;
  ushort ov[8];
  #pragma unroll
  for (int j = 0; j < 8; j++) ov[j] = f2bf(acc[j] * scale);
  *(uint4*)(agg + (size_t)node * HD + l16 * 8) = *(const uint4*)ov;
}

// shared GEMM core: a[8] fragments (K=256) x 64KB swizzled W in 4x16KB stages
__device__ void mono_mma(const bvec8* a, const ushort* __restrict__ W,
                         ushort* sW, int tid, int lane, fvec4* acc){
  #pragma unroll
  for (int s = 0; s < 4; s++){
    __syncthreads();
    #pragma unroll
    for (int it = 0; it < 4; it++){
      int off = it * 2048 + tid * 8;
      *(uint4*)(sW + off) = *(const uint4*)(W + s * 8192 + off);
    }
    __syncthreads();
    #pragma unroll
    for (int k0r = 0; k0r < 2; k0r++){
      #pragma unroll
      for (int t = 0; t < 8; t++){
        bvec8 b = *(const bvec8*)(sW + ((k0r * 8 + t) * 64 + lane) * 8);
        acc[t] = __builtin_amdgcn_mfma_f32_16x16x32_bf16(a[s * 2 + k0r], b, acc[t], 0, 0, 0);
      }
    }
  }
}

__device__ void mono_gemm_tile(int tb, int f32, const void* __restrict__ xin,
                               const ushort* __restrict__ WtA, const float* __restrict__ vecs,
                               const int* __restrict__ node_kind, ushort* __restrict__ h0,
                               ushort* sW, int tid){
  int wave = tid >> 6, lane = tid & 63, quad = lane >> 4, l16 = lane & 15;
  int rb = tb * 64 + wave * 16;
  int arow = rb + l16; if (arow >= N_NODES) arow = N_NODES - 1;
  const ushort* abf = (const ushort*)xin + (size_t)arow * DIN + quad * 8;
  const float*  af  = (const float*)xin + (size_t)arow * DIN + quad * 8;
  bvec8 a[8];
  if (f32){
    #pragma unroll
    for (int k0 = 0; k0 < 8; k0++){
      fvec4 lo = *(const fvec4*)(af + k0 * 32);
      fvec4 hi = *(const fvec4*)(af + k0 * 32 + 4);
      a[k0][0] = (short)f2bf(lo[0]); a[k0][1] = (short)f2bf(lo[1]);
      a[k0][2] = (short)f2bf(lo[2]); a[k0][3] = (short)f2bf(lo[3]);
      a[k0][4] = (short)f2bf(hi[0]); a[k0][5] = (short)f2bf(hi[1]);
      a[k0][6] = (short)f2bf(hi[2]); a[k0][7] = (short)f2bf(hi[3]);
    }
  } else {
    #pragma unroll
    for (int k0 = 0; k0 < 8; k0++) a[k0] = *(const bvec8*)(abf + k0 * 32);
  }
  fvec4 acc[8];
  #pragma unroll
  for (int t = 0; t < 8; t++)
    #pragma unroll
    for (int i = 0; i < 4; i++) acc[t][i] = 0.f;

  mono_mma(a, WtA, sW, tid, lane, acc);

  const float* b_in  = vecs;
  const float* kinde = vecs + 128;
  const float* ext   = vecs + 512;
  #pragma unroll
  for (int i = 0; i < 4; i++){
    int row = rb + quad * 4 + i;
    if (row >= N_NODES) continue;
    int kind = node_kind[row];
    float extf = (kind != 0) ? 1.f : 0.f;
    #pragma unroll
    for (int t = 0; t < 8; t++){
      int col = t * 16 + l16;
      float v = acc[t][i] + b_in[col] + kinde[kind * HD + col] + extf * ext[col];
      h0[(size_t)row * HD + col] = f2bf(v);
    }
  }
}

template<int MODE>
__device__ void mono_conv_tile(int tb, int f32, const ushort* __restrict__ h,
                               const ushort* __restrict__ agg, const ushort* __restrict__ Wc,
                               const float* __restrict__ vecs, void* __restrict__ outp,
                               ushort* sW, int tid){
  int wave = tid >> 6, lane = tid & 63, quad = lane >> 4, l16 = lane & 15;
  int rb = tb * 64 + wave * 16;
  int arow = rb + l16; if (arow >= N_NODES) arow = N_NODES - 1;
  const ushort* ab = agg + (size_t)arow * HD + quad * 8;
  const ushort* hb = h   + (size_t)arow * HD + quad * 8;
  bvec8 a[8];
  #pragma unroll
  for (int j = 0; j < 4; j++) a[j]     = *(const bvec8*)(ab + j * 32);
  #pragma unroll
  for (int j = 0; j < 4; j++) a[4 + j] = *(const bvec8*)(hb + j * 32);
  fvec4 acc[8];
  #pragma unroll
  for (int t = 0; t < 8; t++)
    #pragma unroll
    for (int i = 0; i < 4; i++) acc[t][i] = 0.f;

  mono_mma(a, Wc, sW, tid, lane, acc);

  if (MODE == 1){
    const float* bias   = vecs + 640;
    const float* gammav = vecs + 768;
    const float* betav  = vecs + 896;
    float zv[8][4];
    float s1[4] = {0.f, 0.f, 0.f, 0.f};
    float s2[4] = {0.f, 0.f, 0.f, 0.f};
    #pragma unroll
    for (int t = 0; t < 8; t++){
      float bc = bias[t * 16 + l16];
      #pragma unroll
      for (int i = 0; i < 4; i++){
        float v = acc[t][i] + bc;
        zv[t][i] = v;
        s1[i] += v;
        s2[i] += v * v;
      }
    }
    #pragma unroll
    for (int m = 1; m < 16; m <<= 1){
      #pragma unroll
      for (int i = 0; i < 4; i++){
        s1[i] += __shfl_xor(s1[i], m, 64);
        s2[i] += __shfl_xor(s2[i], m, 64);
      }
    }
    float mu[4], rsv[4];
    #pragma unroll
    for (int i = 0; i < 4; i++){
      mu[i] = s1[i] * (1.f / 128.f);
      float var = s2[i] * (1.f / 128.f) - mu[i] * mu[i];
      rsv[i] = rsqrtf(var + LN_EPS);
    }
    ushort* ob = (ushort*)outp;
    #pragma unroll
    for (int t = 0; t < 8; t++){
      int col = t * 16 + l16;
      float g = gammav[col], bt = betav[col];
      #pragma unroll
      for (int i = 0; i < 4; i++){
        int row = rb + quad * 4 + i;
        if (row >= N_NODES) continue;
        float v = (zv[t][i] - mu[i]) * rsv[i] * g + bt;
        v = fmaxf(v, 0.f);
        ob[(size_t)row * HD + col] = f2bf(v);
      }
    }
  } else {
    const float* bias = vecs + 1024;
    #pragma unroll
    for (int t = 0; t < 8; t++){
      int col = t * 16 + l16;
      float bc = bias[col];
      #pragma unroll
      for (int i = 0; i < 4; i++){
        int row = rb + quad * 4 + i;
        if (row >= N_NODES) continue;
        float v = acc[t][i] + bc;
        if (f32) ((float*)outp)[(size_t)row * HD + col] = v;
        else     ((ushort*)outp)[(size_t)row * HD + col] = f2bf(v);
      }
    }
  }
}

// ================= the cooperative mono-kernel =================
__global__ void __launch_bounds__(256, 6) k_mono(
    const ushort* __restrict__ x, const int* __restrict__ ei,
    const int* __restrict__ node_kind,
    const void* __restrict__ W_in, const void* __restrict__ b_in,
    const void* __restrict__ kind_embed, const void* __restrict__ ext_seed,
    const void* __restrict__ Wl1, const void* __restrict__ bl1, const void* __restrict__ Wr1,
    const void* __restrict__ gammap, const void* __restrict__ betap,
    const void* __restrict__ Wl2, const void* __restrict__ bl2, const void* __restrict__ Wr2,
    int* __restrict__ flag, int* __restrict__ total, int* __restrict__ cnt,
    int* __restrict__ cursor, int* __restrict__ rowstart, int* __restrict__ esrc,
    ushort* __restrict__ WtA, ushort* __restrict__ Wc1, ushort* __restrict__ Wc2,
    float* __restrict__ vecs, ushort* __restrict__ h0, ushort* __restrict__ h1,
    ushort* __restrict__ aggb, int* __restrict__ echunk, void* __restrict__ outp){
  __shared__ __align__(16) ushort sW[8192];   // 16 KB
  __shared__ int chunkId;
  cg::grid_group grid = cg::this_grid();
  const int tid  = threadIdx.x;
  const int bid  = blockIdx.x;
  const int GRID = gridDim.x;
  const int nthr = GRID * 256;
  const int gid  = bid * 256 + tid;
  const int* src = ei;
  const int* dst = ei + N_EDGES;

  // ---- P0: dtype detect (per block), zero CSR state, weight swizzle, vecs ----
  int f32;
  {
    int* red = (int*)sW;
    int c = 0;
    for (int j = 0; j < 8; j++){
      ushort u = x[tid * 8 + j];
      int e2 = (u >> 7) & 0xff;
      if (e2 >= 0x88 || (e2 != 0 && e2 <= 0x70)) c++;
    }
    red[tid] = c;
    __syncthreads();
    for (int off = 128; off > 0; off >>= 1){
      if (tid < off) red[tid] += red[tid + off];
      __syncthreads();
    }
    f32 = (red[0] > 100) ? 1 : 0;
    __syncthreads();
  }
  if (gid == 0){ flag[0] = f32; total[0] = 0; echunk[0] = 0; }
  for (int i = gid; i < N_NODES; i += nthr) cnt[i] = 0;
  if (gid < 128 * 256){
    int idx = gid;
    int c   = idx >> 9;
    int lam = (idx >> 3) & 63;
    int j   = idx & 7;
    int k0  = c >> 3;
    int tt  = c & 7;
    int n   = tt * 16 + (lam & 15);
    int k   = k0 * 32 + (lam >> 4) * 8 + j;
    WtA[idx] = f2bf(rdany(W_in, k * 128 + n, f32));
    if (k < 128){
      Wc1[idx] = f2bf(rdany(Wl1, k * 128 + n, f32));
      Wc2[idx] = f2bf(rdany(Wl2, k * 128 + n, f32));
    } else {
      Wc1[idx] = f2bf(rdany(Wr1, (k - 128) * 128 + n, f32));
      Wc2[idx] = f2bf(rdany(Wr2, (k - 128) * 128 + n, f32));
    }
  }
  if (bid == 0){
    for (int i = tid; i < 1152; i += 256){
      float v;
      if (i < 128)       v = rdany(b_in, i, f32);
      else if (i < 512)  v = rdany(kind_embed, i - 128, f32);
      else if (i < 640)  v = rdany(ext_seed, i - 512, f32);
      else if (i < 768)  v = rdany(bl1, i - 640, f32);
      else if (i < 896)  v = rdany(gammap, i - 768, f32);
      else if (i < 1024) v = rdany(betap, i - 896, f32);
      else               v = rdany(bl2, i - 1024, f32);
      vecs[i] = v;
    }
  }
  __threadfence(); grid.sync();

  // ---- P1: edge count histogram ----
  for (int e = gid; e < N_EDGES; e += nthr) atomicAdd(&cnt[dst[e]], 1);
  __threadfence(); grid.sync();

  // ---- P2: CSR scan (wave scan + atomic base; primes cursor) ----
  {
    int lane = tid & 63;
    int i = gid;                      // nthr >= N_NODES guaranteed (grid >= 256 blocks)
    int c = (i < N_NODES) ? cnt[i] : 0;
    int scan = c;
    #pragma unroll
    for (int m = 1; m < 64; m <<= 1){
      int v = __shfl_up(scan, m, 64);
      if (lane >= m) scan += v;
    }
    int wave_total = __shfl(scan, 63, 64);
    int base = 0;
    if (lane == 63) base = atomicAdd(total, wave_total);
    base = __shfl(base, 63, 64);
    if (i < N_NODES){
      int rsv = base + scan - c;
      rowstart[i] = rsv;
      cursor[i]   = rsv;
    }
  }
  __threadfence(); grid.sync();

  // ---- P3: input GEMM (tile-stride) + CSR fill (chunk work-stealing) ----
  for (int tb = bid; tb < GEMM_GRID; tb += GRID)
    mono_gemm_tile(tb, f32, (const void*)x, WtA, vecs, node_kind, h0, sW, tid);
  while (true){
    __syncthreads();
    if (tid == 0) chunkId = atomicAdd(echunk, 1);
    __syncthreads();
    int c = chunkId;
    if (c >= FILL_CHUNKS) break;
    int base = c * 4096;
    #pragma unroll
    for (int j = 0; j < 16; j++){
      int e = base + j * 256 + tid;
      if (e < N_EDGES){
        int d = dst[e];
        int pos = atomicAdd(&cursor[d], 1);
        esrc[pos] = src[e];
      }
    }
  }
  __threadfence(); grid.sync();

  // ---- P4: gather 1 ----
  {
    int q = gid >> 4, l16 = tid & 15, nq = nthr >> 4;
    for (int node = q; node < N_NODES; node += nq)
      mono_gather(node, l16, h0, rowstart, cnt, esrc, aggb);
  }
  __threadfence(); grid.sync();

  // ---- P5: conv 1 (LN + ReLU) ----
  for (int tb = bid; tb < GEMM_GRID; tb += GRID)
    mono_conv_tile<1>(tb, f32, h0, aggb, Wc1, vecs, (void*)h1, sW, tid);
  __threadfence(); grid.sync();

  // ---- P6: gather 2 ----
  {
    int q = gid >> 4, l16 = tid & 15, nq = nthr >> 4;
    for (int node = q; node < N_NODES; node += nq)
      mono_gather(node, l16, h1, rowstart, cnt, esrc, aggb);
  }
  __threadfence(); grid.sync();

  // ---- P7: conv 2 -> output ----
  for (int tb = bid; tb < GEMM_GRID; tb += GRID)
    mono_conv_tile<2>(tb, f32, h1, aggb, Wc2, vecs, outp, sW, tid);
}

// ================= fallback path (round-5 kernels, verbatim) =================

__global__ void k_zero(int* __restrict__ cnt, int* __restrict__ total){
  int i = blockIdx.x * 256 + threadIdx.x;
  if (i < N_NODES) cnt[i] = 0;
  if (i == 0) total[0] = 0;
}

__global__ void k_prep_count(const ushort* __restrict__ x, int* __restrict__ flag,
                             const int* __restrict__ dst, int* __restrict__ cnt,
                             const void* __restrict__ W_in,
                             const void* __restrict__ Wl1, const void* __restrict__ Wr1,
                             const void* __restrict__ Wl2, const void* __restrict__ Wr2,
                             ushort* __restrict__ WtA, ushort* __restrict__ Wc1, ushort* __restrict__ Wc2,
                             const void* b_in, const void* kind_embed, const void* ext_seed,
                             const void* bl1, const void* gammap, const void* betap,
                             const void* bl2, float* __restrict__ vecs){
  if (blockIdx.x >= 128){
    int e = (blockIdx.x - 128) * 256 + threadIdx.x;
    if (e < N_EDGES) atomicAdd(&cnt[dst[e]], 1);
    return;
  }
  __shared__ int red[256];
  int t = threadIdx.x;
  {
    int c = 0;
    for (int j = 0; j < 8; j++){
      ushort u = x[t * 8 + j];
      int e = (u >> 7) & 0xff;
      if (e >= 0x88 || (e != 0 && e <= 0x70)) c++;
    }
    red[t] = c;
    __syncthreads();
    for (int off = 128; off > 0; off >>= 1){
      if (t < off) red[t] += red[t + off];
      __syncthreads();
    }
  }
  int f32 = (red[0] > 100) ? 1 : 0;
  if (blockIdx.x == 0 && t == 0) flag[0] = f32;

  int idx = blockIdx.x * 256 + t;
  {
    int c   = idx >> 9;
    int lam = (idx >> 3) & 63;
    int j   = idx & 7;
    int k0  = c >> 3;
    int tt  = c & 7;
    int n   = tt * 16 + (lam & 15);
    int k   = k0 * 32 + (lam >> 4) * 8 + j;
    WtA[idx] = f2bf(rdany(W_in, k * 128 + n, f32));
    if (k < 128){
      Wc1[idx] = f2bf(rdany(Wl1, k * 128 + n, f32));
      Wc2[idx] = f2bf(rdany(Wl2, k * 128 + n, f32));
    } else {
      Wc1[idx] = f2bf(rdany(Wr1, (k - 128) * 128 + n, f32));
      Wc2[idx] = f2bf(rdany(Wr2, (k - 128) * 128 + n, f32));
    }
  }
  if (blockIdx.x == 0){
    for (int i = t; i < 1152; i += 256){
      float v;
      if (i < 128)       v = rdany(b_in, i, f32);
      else if (i < 512)  v = rdany(kind_embed, i - 128, f32);
      else if (i < 640)  v = rdany(ext_seed, i - 512, f32);
      else if (i < 768)  v = rdany(bl1, i - 640, f32);
      else if (i < 896)  v = rdany(gammap, i - 768, f32);
      else if (i < 1024) v = rdany(betap, i - 896, f32);
      else               v = rdany(bl2, i - 1024, f32);
      vecs[i] = v;
    }
  }
}

__global__ void k_assign(const int* __restrict__ cnt, int* __restrict__ rowstart,
                         int* __restrict__ cursor, int* __restrict__ total){
  int i = blockIdx.x * 256 + threadIdx.x;
  int lane = threadIdx.x & 63;
  int c = (i < N_NODES) ? cnt[i] : 0;
  int scan = c;
  #pragma unroll
  for (int m = 1; m < 64; m <<= 1){
    int v = __shfl_up(scan, m, 64);
    if (lane >= m) scan += v;
  }
  int wave_total = __shfl(scan, 63, 64);
  int base = 0;
  if (lane == 63) base = atomicAdd(total, wave_total);
  base = __shfl(base, 63, 64);
  if (i < N_NODES){
    int rsv = base + scan - c;
    rowstart[i] = rsv;
    cursor[i]   = rsv;
  }
}

__global__ void __launch_bounds__(256) k_gemm_fill(
    const int* __restrict__ flag, const void* __restrict__ xin,
    const ushort* __restrict__ WtA, const float* __restrict__ vecs,
    const int* __restrict__ node_kind, ushort* __restrict__ h0,
    const int* __restrict__ src, const int* __restrict__ dst,
    int* __restrict__ cursor, int* __restrict__ esrc){
  __shared__ __align__(16) ushort sW[16384];
  if (blockIdx.x >= GEMM_GRID){
    int e = (blockIdx.x - GEMM_GRID) * 256 + threadIdx.x;
    if (e < N_EDGES){
      int d = dst[e];
      int pos = atomicAdd(&cursor[d], 1);
      esrc[pos] = src[e];
    }
    return;
  }
  int f32 = flag[0];
  int tid  = threadIdx.x;
  int wave = tid >> 6;
  int lane = tid & 63;
  int quad = lane >> 4;
  int l16  = lane & 15;
  int rb = blockIdx.x * 64 + wave * 16;

  fvec4 acc[8];
  #pragma unroll
  for (int t = 0; t < 8; t++)
    #pragma unroll
    for (int i = 0; i < 4; i++) acc[t][i] = 0.f;

  int arow = rb + l16; if (arow >= N_NODES) arow = N_NODES - 1;
  const ushort* abf = (const ushort*)xin + (size_t)arow * DIN + quad * 8;
  const float*  af  = (const float*)xin + (size_t)arow * DIN + quad * 8;

  bvec8 a[8];
  if (f32){
    #pragma unroll
    for (int k0 = 0; k0 < 8; k0++){
      fvec4 lo = *(const fvec4*)(af + k0 * 32);
      fvec4 hi = *(const fvec4*)(af + k0 * 32 + 4);
      a[k0][0] = (short)f2bf(lo[0]); a[k0][1] = (short)f2bf(lo[1]);
      a[k0][2] = (short)f2bf(lo[2]); a[k0][3] = (short)f2bf(lo[3]);
      a[k0][4] = (short)f2bf(hi[0]); a[k0][5] = (short)f2bf(hi[1]);
      a[k0][6] = (short)f2bf(hi[2]); a[k0][7] = (short)f2bf(hi[3]);
    }
  } else {
    #pragma unroll
    for (int k0 = 0; k0 < 8; k0++) a[k0] = *(const bvec8*)(abf + k0 * 32);
  }

  #pragma unroll
  for (int s = 0; s < 2; s++){
    if (s) __syncthreads();
    #pragma unroll
    for (int it = 0; it < 8; it++){
      int off = it * 2048 + tid * 8;
      *(uint4*)(sW + off) = *(const uint4*)(WtA + s * 16384 + off);
    }
    __syncthreads();
    #pragma unroll
    for (int k0 = 0; k0 < 4; k0++){
      #pragma unroll
      for (int t = 0; t < 8; t++){
        bvec8 b = *(const bvec8*)(sW + ((k0 * 8 + t) * 64 + lane) * 8);
        acc[t] = __builtin_amdgcn_mfma_f32_16x16x32_bf16(a[s * 4 + k0], b, acc[t], 0, 0, 0);
      }
    }
  }

  const float* b_in  = vecs;
  const float* kinde = vecs + 128;
  const float* ext   = vecs + 512;
  #pragma unroll
  for (int i = 0; i < 4; i++){
    int row = rb + quad * 4 + i;
    if (row >= N_NODES) continue;
    int kind = node_kind[row];
    float extf = (kind != 0) ? 1.f : 0.f;
    #pragma unroll
    for (int t = 0; t < 8; t++){
      int col = t * 16 + l16;
      float v = acc[t][i] + b_in[col] + kinde[kind * HD + col] + extf * ext[col];
      h0[(size_t)row * HD + col] = f2bf(v);
    }
  }
}

__global__ void __launch_bounds__(256) k_gather(
    const ushort* __restrict__ h, const int* __restrict__ rowstart,
    const int* __restrict__ cnt, const int* __restrict__ esrc,
    ushort* __restrict__ agg){
  int tid  = threadIdx.x;
  int node = blockIdx.x * 16 + (tid >> 4);
  int l16  = tid & 15;
  if (node >= N_NODES) return;
  mono_gather(node, l16, h, rowstart, cnt, esrc, agg);
}

template<int MODE>
__global__ void __launch_bounds__(256) k_conv(
    const int* __restrict__ flag, const ushort* __restrict__ h,
    const ushort* __restrict__ agg,
    const ushort* __restrict__ Wc, const float* __restrict__ vecs,
    void* __restrict__ outp){
  __shared__ __align__(16) ushort sW[16384];
  int f32 = flag[0];
  int tid  = threadIdx.x;
  int wave = tid >> 6;
  int lane = tid & 63;
  int quad = lane >> 4;
  int l16  = lane & 15;
  int rb  = blockIdx.x * 64 + wave * 16;

  int arow = rb + l16; if (arow >= N_NODES) arow = N_NODES - 1;
  const ushort* ab = agg + (size_t)arow * HD + quad * 8;
  const ushort* hb = h   + (size_t)arow * HD + quad * 8;
  bvec8 a[8];
  #pragma unroll
  for (int j = 0; j < 4; j++) a[j]     = *(const bvec8*)(ab + j * 32);
  #pragma unroll
  for (int j = 0; j < 4; j++) a[4 + j] = *(const bvec8*)(hb + j * 32);

  fvec4 acc[8];
  #pragma unroll
  for (int t = 0; t < 8; t++)
    #pragma unroll
    for (int i = 0; i < 4; i++) acc[t][i] = 0.f;

  #pragma unroll
  for (int s = 0; s < 2; s++){
    if (s) __syncthreads();
    #pragma unroll
    for (int it = 0; it < 8; it++){
      int off = it * 2048 + tid * 8;
      *(uint4*)(sW + off) = *(const uint4*)(Wc + s * 16384 + off);
    }
    __syncthreads();
    #pragma unroll
    for (int k0 = 0; k0 < 4; k0++){
      #pragma unroll
      for (int t = 0; t < 8; t++){
        bvec8 b = *(const bvec8*)(sW + ((k0 * 8 + t) * 64 + lane) * 8);
        acc[t] = __builtin_amdgcn_mfma_f32_16x16x32_bf16(a[s * 4 + k0], b, acc[t], 0, 0, 0);
      }
    }
  }

  if (MODE == 1){
    const float* bias   = vecs + 640;
    const float* gammav = vecs + 768;
    const float* betav  = vecs + 896;
    float zv[8][4];
    float s1[4] = {0.f, 0.f, 0.f, 0.f};
    float s2[4] = {0.f, 0.f, 0.f, 0.f};
    #pragma unroll
    for (int t = 0; t < 8; t++){
      float bc = bias[t * 16 + l16];
      #pragma unroll
      for (int i = 0; i < 4; i++){
        float v = acc[t][i] + bc;
        zv[t][i] = v;
        s1[i] += v;
        s2[i] += v * v;
      }
    }
    #pragma unroll
    for (int m = 1; m < 16; m <<= 1){
      #pragma unroll
      for (int i = 0; i < 4; i++){
        s1[i] += __shfl_xor(s1[i], m, 64);
        s2[i] += __shfl_xor(s2[i], m, 64);
      }
    }
    float mu[4], rsv[4];
    #pragma unroll
    for (int i = 0; i < 4; i++){
      mu[i] = s1[i] * (1.f / 128.f);
      float var = s2[i] * (1.f / 128.f) - mu[i] * mu[i];
      rsv[i] = rsqrtf(var + LN_EPS);
    }
    ushort* ob = (ushort*)outp;
    #pragma unroll
    for (int t = 0; t < 8; t++){
      int col = t * 16 + l16;
      float g = gammav[col], bt = betav[col];
      #pragma unroll
      for (int i = 0; i < 4; i++){
        int row = rb + quad * 4 + i;
        if (row >= N_NODES) continue;
        float v = (zv[t][i] - mu[i]) * rsv[i] * g + bt;
        v = fmaxf(v, 0.f);
        ob[(size_t)row * HD + col] = f2bf(v);
      }
    }
  } else {
    const float* bias = vecs + 1024;
    #pragma unroll
    for (int t = 0; t < 8; t++){
      int col = t * 16 + l16;
      float bc = bias[col];
      #pragma unroll
      for (int i = 0; i < 4; i++){
        int row = rb + quad * 4 + i;
        if (row >= N_NODES) continue;
        float v = acc[t][i] + bc;
        if (f32) ((float*)outp)[(size_t)row * HD + col] = v;
        else     ((ushort*)outp)[(size_t)row * HD + col] = f2bf(v);
      }
    }
  }
}

extern "C" void kernel_launch(void* const* d_in, const int* in_sizes, int n_in,
                              void* d_out, int out_size, void* d_ws, size_t ws_size,
                              hipStream_t stream) {
  const void* x          = d_in[0];
  const int*  ei         = (const int*)d_in[1];
  const int*  node_kind  = (const int*)d_in[2];
  const void* W_in       = d_in[3];
  const void* b_in       = d_in[4];
  const void* kind_embed = d_in[5];
  const void* ext_seed   = d_in[6];
  const void* Wl1        = d_in[7];
  const void* bl1        = d_in[8];
  const void* Wr1        = d_in[9];
  const void* gammap     = d_in[10];
  const void* betap      = d_in[11];
  const void* Wl2        = d_in[12];
  const void* bl2        = d_in[13];
  const void* Wr2        = d_in[14];
  const int* src = ei;
  const int* dst = ei + N_EDGES;

  char* ws = (char*)d_ws;
  size_t off = 0;
  auto alloc = [&](size_t bytes) -> void* {
    void* p = ws + off;
    off += (bytes + 255) & ~(size_t)255;
    return p;
  };
  int*    flag     = (int*)alloc(256);
  int*    total    = (int*)alloc(256);
  int*    cnt      = (int*)alloc(N_NODES * 4);
  int*    cursor   = (int*)alloc(N_NODES * 4);
  int*    rowstart = (int*)alloc(N_NODES * 4);
  int*    esrc     = (int*)alloc(N_EDGES * 4);
  ushort* WtA      = (ushort*)alloc(128 * 256 * 2);
  ushort* Wc1      = (ushort*)alloc(128 * 256 * 2);
  ushort* Wc2      = (ushort*)alloc(128 * 256 * 2);
  float*  vecs     = (float*)alloc(1152 * 4);
  ushort* h0       = (ushort*)alloc((size_t)N_NODES * HD * 2);
  ushort* h1       = (ushort*)alloc((size_t)N_NODES * HD * 2);
  ushort* aggb     = (ushort*)alloc((size_t)N_NODES * HD * 2);
  int*    echunk   = (int*)alloc(256);

  // ---- try single cooperative mono-kernel; fall back to 8-launch path ----
  int use_coop = 0;
  {
    int dev = 0;
    (void)hipGetDevice(&dev);
    int attr = 0;
    if (hipDeviceGetAttribute(&attr, hipDeviceAttributeCooperativeLaunch, dev) == hipSuccess)
      use_coop = attr;
  }
  int grid = MONO_GRID;
  if (use_coop){
    int maxb = 0;
    if (hipOccupancyMaxActiveBlocksPerMultiprocessor(&maxb, (const void*)k_mono, 256, 0) == hipSuccess
        && maxb > 0){
      int cap = maxb * 256;          // 256 CUs
      if (grid > cap) grid = cap;
    }
    if (grid < 256) use_coop = 0;    // phases assume nthr >= N_NODES
  }
  if (use_coop){
    const ushort* xus = (const ushort*)x;
    void* outp = d_out;
    void* params[] = {
      (void*)&xus, (void*)&ei, (void*)&node_kind,
      (void*)&W_in, (void*)&b_in, (void*)&kind_embed, (void*)&ext_seed,
      (void*)&Wl1, (void*)&bl1, (void*)&Wr1,
      (void*)&gammap, (void*)&betap,
      (void*)&Wl2, (void*)&bl2, (void*)&Wr2,
      (void*)&flag, (void*)&total, (void*)&cnt, (void*)&cursor, (void*)&rowstart,
      (void*)&esrc, (void*)&WtA, (void*)&Wc1, (void*)&Wc2, (void*)&vecs,
      (void*)&h0, (void*)&h1, (void*)&aggb, (void*)&echunk, (void*)&outp };
    hipError_t err = hipLaunchCooperativeKernel((const void*)k_mono, dim3(grid), dim3(256),
                                                params, 0, stream);
    if (err == hipSuccess) return;
    use_coop = 0;   // fall through to classic path
  }

  k_zero<<<NODE_GRID, 256, 0, stream>>>(cnt, total);
  k_prep_count<<<128 + EDGE_GRID, 256, 0, stream>>>((const ushort*)x, flag, dst, cnt,
                                                    W_in, Wl1, Wr1, Wl2, Wr2, WtA, Wc1, Wc2,
                                                    b_in, kind_embed, ext_seed, bl1, gammap, betap, bl2, vecs);
  k_assign<<<NODE_GRID, 256, 0, stream>>>(cnt, rowstart, cursor, total);
  k_gemm_fill<<<GEMM_GRID + EDGE_GRID, 256, 0, stream>>>(flag, x, WtA, vecs, node_kind, h0,
                                                         src, dst, cursor, esrc);
  int gath_grid = (N_NODES + 15) / 16;
  k_gather<<<gath_grid, 256, 0, stream>>>(h0, rowstart, cnt, esrc, aggb);
  k_conv<1><<<GEMM_GRID, 256, 0, stream>>>(flag, h0, aggb, Wc1, vecs, (void*)h1);
  k_gather<<<gath_grid, 256, 0, stream>>>(h1, rowstart, cnt, esrc, aggb);
  k_conv<2><<<GEMM_GRID, 256, 0, stream>>>(flag, h1, aggb, Wc2, vecs, d_out);
}

// Round 7
// 452.282 us; speedup vs baseline: 3.2516x; 3.2516x over previous
//
#include <hip/hip_runtime.h>
#include <hip/hip_cooperative_groups.h>
#include <stdint.h>

namespace cg = cooperative_groups;

#define N_NODES 50000
#define N_EDGES 625000
#define DIN 256
#define HD 128
#define LN_EPS 1e-5f

#define GEMM_GRID 782      // (N_NODES+63)/64
#define EDGE_GRID 2442     // (N_EDGES+255)/256
#define NODE_GRID 196      // (N_NODES+255)/256
#define FILL_CHUNKS 153    // ceil(625000/4096)
#define PRE_GRID 1024      // 4 blocks/CU x 256 CUs (all-resident for grid.sync)

typedef __attribute__((ext_vector_type(8))) short bvec8;
typedef __attribute__((ext_vector_type(4))) float fvec4;

__device__ inline float bf2f(ushort u){
  union { uint32_t u32; float f; } c; c.u32 = ((uint32_t)u) << 16; return c.f;
}
__device__ inline ushort f2bf(float f){
  union { float f; uint32_t u; } c; c.f = f;
  uint32_t u = c.u;
  return (ushort)((u + 0x7fffu + ((u >> 16) & 1u)) >> 16);
}
__device__ inline float rdany(const void* p, int i, int f32){
  return f32 ? ((const float*)p)[i] : bf2f(((const ushort*)p)[i]);
}

// ---------------- shared device body: one 64-row input-GEMM tile ----------------
// 32KB half-staged weights; barrier at stage top makes multi-tile reuse safe.
__device__ void gemm_tile_body(int tb, int f32, const void* __restrict__ xin,
                               const ushort* __restrict__ WtA, const float* __restrict__ vecs,
                               const int* __restrict__ node_kind, ushort* __restrict__ h0,
                               ushort* sW, int tid){
  int wave = tid >> 6, lane = tid & 63, quad = lane >> 4, l16 = lane & 15;
  int rb = tb * 64 + wave * 16;
  int arow = rb + l16; if (arow >= N_NODES) arow = N_NODES - 1;
  const ushort* abf = (const ushort*)xin + (size_t)arow * DIN + quad * 8;
  const float*  af  = (const float*)xin + (size_t)arow * DIN + quad * 8;
  bvec8 a[8];
  if (f32){
    #pragma unroll
    for (int k0 = 0; k0 < 8; k0++){
      fvec4 lo = *(const fvec4*)(af + k0 * 32);
      fvec4 hi = *(const fvec4*)(af + k0 * 32 + 4);
      a[k0][0] = (short)f2bf(lo[0]); a[k0][1] = (short)f2bf(lo[1]);
      a[k0][2] = (short)f2bf(lo[2]); a[k0][3] = (short)f2bf(lo[3]);
      a[k0][4] = (short)f2bf(hi[0]); a[k0][5] = (short)f2bf(hi[1]);
      a[k0][6] = (short)f2bf(hi[2]); a[k0][7] = (short)f2bf(hi[3]);
    }
  } else {
    #pragma unroll
    for (int k0 = 0; k0 < 8; k0++) a[k0] = *(const bvec8*)(abf + k0 * 32);
  }
  fvec4 acc[8];
  #pragma unroll
  for (int t = 0; t < 8; t++)
    #pragma unroll
    for (int i = 0; i < 4; i++) acc[t][i] = 0.f;

  #pragma unroll
  for (int s = 0; s < 2; s++){
    __syncthreads();
    #pragma unroll
    for (int it = 0; it < 8; it++){
      int off = it * 2048 + tid * 8;
      *(uint4*)(sW + off) = *(const uint4*)(WtA + s * 16384 + off);
    }
    __syncthreads();
    #pragma unroll
    for (int k0 = 0; k0 < 4; k0++){
      #pragma unroll
      for (int t = 0; t < 8; t++){
        bvec8 b = *(const bvec8*)(sW + ((k0 * 8 + t) * 64 + lane) * 8);
        acc[t] = __builtin_amdgcn_mfma_f32_16x16x32_bf16(a[s * 4 + k0], b, acc[t], 0, 0, 0);
      }
    }
  }

  const float* b_in  = vecs;
  const float* kinde = vecs + 128;
  const float* ext   = vecs + 512;
  #pragma unroll
  for (int i = 0; i < 4; i++){
    int row = rb + quad * 4 + i;
    if (row >= N_NODES) continue;
    int kind = node_kind[row];
    float extf = (kind != 0) ? 1.f : 0.f;
    #pragma unroll
    for (int t = 0; t < 8; t++){
      int col = t * 16 + l16;
      float v = acc[t][i] + b_in[col] + kinde[kind * HD + col] + extf * ext[col];
      h0[(size_t)row * HD + col] = f2bf(v);
    }
  }
}

// ================= cooperative preprocessing kernel =================
// P0: dtype detect + zero CSR state + weight swizzle + vecs
// P1: edge-count histogram        P2: CSR scan (primes cursor)
// P3: input GEMM (tile-stride) || CSR fill (chunk work-stealing)
__global__ void __launch_bounds__(256, 4) k_pre(
    const ushort* __restrict__ x, const int* __restrict__ ei,
    const int* __restrict__ node_kind,
    const void* __restrict__ W_in, const void* __restrict__ b_in,
    const void* __restrict__ kind_embed, const void* __restrict__ ext_seed,
    const void* __restrict__ Wl1, const void* __restrict__ bl1, const void* __restrict__ Wr1,
    const void* __restrict__ gammap, const void* __restrict__ betap,
    const void* __restrict__ Wl2, const void* __restrict__ bl2, const void* __restrict__ Wr2,
    int* __restrict__ flag, int* __restrict__ total, int* __restrict__ cnt,
    int* __restrict__ cursor, int* __restrict__ rowstart, int* __restrict__ esrc,
    ushort* __restrict__ WtA, ushort* __restrict__ Wc1, ushort* __restrict__ Wc2,
    float* __restrict__ vecs, ushort* __restrict__ h0, int* __restrict__ echunk){
  __shared__ __align__(16) ushort sW[16384];   // 32 KB, reused across phases
  __shared__ int chunkId;
  cg::grid_group grid = cg::this_grid();
  const int tid  = threadIdx.x;
  const int bid  = blockIdx.x;
  const int GRID = gridDim.x;
  const int nthr = GRID * 256;
  const int gid  = bid * 256 + tid;
  const int* src = ei;
  const int* dst = ei + N_EDGES;

  // ---- P0 ----
  int f32;
  {
    int* red = (int*)sW;
    int c = 0;
    for (int j = 0; j < 8; j++){
      ushort u = x[tid * 8 + j];
      int e2 = (u >> 7) & 0xff;
      if (e2 >= 0x88 || (e2 != 0 && e2 <= 0x70)) c++;
    }
    red[tid] = c;
    __syncthreads();
    for (int off = 128; off > 0; off >>= 1){
      if (tid < off) red[tid] += red[tid + off];
      __syncthreads();
    }
    f32 = (red[0] > 100) ? 1 : 0;
    __syncthreads();
  }
  if (gid == 0){ flag[0] = f32; total[0] = 0; echunk[0] = 0; }
  for (int i = gid; i < N_NODES; i += nthr) cnt[i] = 0;
  if (gid < 128 * 256){
    int idx = gid;
    int c   = idx >> 9;
    int lam = (idx >> 3) & 63;
    int j   = idx & 7;
    int k0  = c >> 3;
    int tt  = c & 7;
    int n   = tt * 16 + (lam & 15);
    int k   = k0 * 32 + (lam >> 4) * 8 + j;
    WtA[idx] = f2bf(rdany(W_in, k * 128 + n, f32));
    if (k < 128){
      Wc1[idx] = f2bf(rdany(Wl1, k * 128 + n, f32));
      Wc2[idx] = f2bf(rdany(Wl2, k * 128 + n, f32));
    } else {
      Wc1[idx] = f2bf(rdany(Wr1, (k - 128) * 128 + n, f32));
      Wc2[idx] = f2bf(rdany(Wr2, (k - 128) * 128 + n, f32));
    }
  }
  if (bid == 0){
    for (int i = tid; i < 1152; i += 256){
      float v;
      if (i < 128)       v = rdany(b_in, i, f32);
      else if (i < 512)  v = rdany(kind_embed, i - 128, f32);
      else if (i < 640)  v = rdany(ext_seed, i - 512, f32);
      else if (i < 768)  v = rdany(bl1, i - 640, f32);
      else if (i < 896)  v = rdany(gammap, i - 768, f32);
      else if (i < 1024) v = rdany(betap, i - 896, f32);
      else               v = rdany(bl2, i - 1024, f32);
      vecs[i] = v;
    }
  }
  __threadfence(); grid.sync();

  // ---- P1: histogram ----
  for (int e = gid; e < N_EDGES; e += nthr) atomicAdd(&cnt[dst[e]], 1);
  __threadfence(); grid.sync();

  // ---- P2: scan (nthr >= N_NODES guaranteed by launcher) ----
  {
    int lane = tid & 63;
    int i = gid;
    int c = (i < N_NODES) ? cnt[i] : 0;
    int scan = c;
    #pragma unroll
    for (int m = 1; m < 64; m <<= 1){
      int v = __shfl_up(scan, m, 64);
      if (lane >= m) scan += v;
    }
    int wave_total = __shfl(scan, 63, 64);
    int base = 0;
    if (lane == 63) base = atomicAdd(total, wave_total);
    base = __shfl(base, 63, 64);
    if (i < N_NODES){
      int rsv = base + scan - c;
      rowstart[i] = rsv;
      cursor[i]   = rsv;
    }
  }
  __threadfence(); grid.sync();

  // ---- P3: gemm tiles, then chunk-steal the fill ----
  for (int tb = bid; tb < GEMM_GRID; tb += GRID)
    gemm_tile_body(tb, f32, (const void*)x, WtA, vecs, node_kind, h0, sW, tid);
  while (true){
    __syncthreads();
    if (tid == 0) chunkId = atomicAdd(echunk, 1);
    __syncthreads();
    int c = chunkId;
    if (c >= FILL_CHUNKS) break;
    int base = c * 4096;
    #pragma unroll
    for (int j = 0; j < 16; j++){
      int e = base + j * 256 + tid;
      if (e < N_EDGES){
        int d = dst[e];
        int pos = atomicAdd(&cursor[d], 1);
        esrc[pos] = src[e];
      }
    }
  }
}

// ================= fallback preprocessing (round-5 kernels) =================

__global__ void k_zero(int* __restrict__ cnt, int* __restrict__ total){
  int i = blockIdx.x * 256 + threadIdx.x;
  if (i < N_NODES) cnt[i] = 0;
  if (i == 0) total[0] = 0;
}

__global__ void k_prep_count(const ushort* __restrict__ x, int* __restrict__ flag,
                             const int* __restrict__ dst, int* __restrict__ cnt,
                             const void* __restrict__ W_in,
                             const void* __restrict__ Wl1, const void* __restrict__ Wr1,
                             const void* __restrict__ Wl2, const void* __restrict__ Wr2,
                             ushort* __restrict__ WtA, ushort* __restrict__ Wc1, ushort* __restrict__ Wc2,
                             const void* b_in, const void* kind_embed, const void* ext_seed,
                             const void* bl1, const void* gammap, const void* betap,
                             const void* bl2, float* __restrict__ vecs){
  if (blockIdx.x >= 128){
    int e = (blockIdx.x - 128) * 256 + threadIdx.x;
    if (e < N_EDGES) atomicAdd(&cnt[dst[e]], 1);
    return;
  }
  __shared__ int red[256];
  int t = threadIdx.x;
  {
    int c = 0;
    for (int j = 0; j < 8; j++){
      ushort u = x[t * 8 + j];
      int e = (u >> 7) & 0xff;
      if (e >= 0x88 || (e != 0 && e <= 0x70)) c++;
    }
    red[t] = c;
    __syncthreads();
    for (int off = 128; off > 0; off >>= 1){
      if (t < off) red[t] += red[t + off];
      __syncthreads();
    }
  }
  int f32 = (red[0] > 100) ? 1 : 0;
  if (blockIdx.x == 0 && t == 0) flag[0] = f32;

  int idx = blockIdx.x * 256 + t;
  {
    int c   = idx >> 9;
    int lam = (idx >> 3) & 63;
    int j   = idx & 7;
    int k0  = c >> 3;
    int tt  = c & 7;
    int n   = tt * 16 + (lam & 15);
    int k   = k0 * 32 + (lam >> 4) * 8 + j;
    WtA[idx] = f2bf(rdany(W_in, k * 128 + n, f32));
    if (k < 128){
      Wc1[idx] = f2bf(rdany(Wl1, k * 128 + n, f32));
      Wc2[idx] = f2bf(rdany(Wl2, k * 128 + n, f32));
    } else {
      Wc1[idx] = f2bf(rdany(Wr1, (k - 128) * 128 + n, f32));
      Wc2[idx] = f2bf(rdany(Wr2, (k - 128) * 128 + n, f32));
    }
  }
  if (blockIdx.x == 0){
    for (int i = t; i < 1152; i += 256){
      float v;
      if (i < 128)       v = rdany(b_in, i, f32);
      else if (i < 512)  v = rdany(kind_embed, i - 128, f32);
      else if (i < 640)  v = rdany(ext_seed, i - 512, f32);
      else if (i < 768)  v = rdany(bl1, i - 640, f32);
      else if (i < 896)  v = rdany(gammap, i - 768, f32);
      else if (i < 1024) v = rdany(betap, i - 896, f32);
      else               v = rdany(bl2, i - 1024, f32);
      vecs[i] = v;
    }
  }
}

__global__ void k_assign(const int* __restrict__ cnt, int* __restrict__ rowstart,
                         int* __restrict__ cursor, int* __restrict__ total){
  int i = blockIdx.x * 256 + threadIdx.x;
  int lane = threadIdx.x & 63;
  int c = (i < N_NODES) ? cnt[i] : 0;
  int scan = c;
  #pragma unroll
  for (int m = 1; m < 64; m <<= 1){
    int v = __shfl_up(scan, m, 64);
    if (lane >= m) scan += v;
  }
  int wave_total = __shfl(scan, 63, 64);
  int base = 0;
  if (lane == 63) base = atomicAdd(total, wave_total);
  base = __shfl(base, 63, 64);
  if (i < N_NODES){
    int rsv = base + scan - c;
    rowstart[i] = rsv;
    cursor[i]   = rsv;
  }
}

__global__ void __launch_bounds__(256) k_gemm_fill(
    const int* __restrict__ flag, const void* __restrict__ xin,
    const ushort* __restrict__ WtA, const float* __restrict__ vecs,
    const int* __restrict__ node_kind, ushort* __restrict__ h0,
    const int* __restrict__ src, const int* __restrict__ dst,
    int* __restrict__ cursor, int* __restrict__ esrc){
  __shared__ __align__(16) ushort sW[16384];
  if (blockIdx.x >= GEMM_GRID){
    int e = (blockIdx.x - GEMM_GRID) * 256 + threadIdx.x;
    if (e < N_EDGES){
      int d = dst[e];
      int pos = atomicAdd(&cursor[d], 1);
      esrc[pos] = src[e];
    }
    return;
  }
  gemm_tile_body(blockIdx.x, flag[0], xin, WtA, vecs, node_kind, h0, sW, threadIdx.x);
}

// ---------------- standalone gather: one 16-lane quad per node ----------------
__global__ void __launch_bounds__(256) k_gather(
    const ushort* __restrict__ h, const int* __restrict__ rowstart,
    const int* __restrict__ cnt, const int* __restrict__ esrc,
    ushort* __restrict__ agg){
  int tid  = threadIdx.x;
  int node = blockIdx.x * 16 + (tid >> 4);
  int l16  = tid & 15;
  if (node >= N_NODES) return;
  int b   = rowstart[node];
  int deg = cnt[node];
  int e   = b + deg;
  float acc[8];
  #pragma unroll
  for (int j = 0; j < 8; j++) acc[j] = 0.f;
  for (int i = b; i < e; i += 8){
    int idx[8];
    #pragma unroll
    for (int k = 0; k < 8; k++){
      int ee = i + k;
      idx[k] = esrc[ee < e ? ee : e - 1];
    }
    uint4 r[8];
    #pragma unroll
    for (int k = 0; k < 8; k++)
      r[k] = *(const uint4*)(h + (size_t)idx[k] * HD + l16 * 8);
    #pragma unroll
    for (int k = 0; k < 8; k++){
      if (i + k < e){
        const uint32_t* w = (const uint32_t*)&r[k];
        #pragma unroll
        for (int j = 0; j < 4; j++){
          acc[2*j]   += bf2f((ushort)(w[j] & 0xffffu));
          acc[2*j+1] += bf2f((ushort)(w[j] >> 16));
        }
      }
    }
  }
  float scale = (deg > 0) ? 1.f / (float)deg : 0.f;
  ushort ov[8];
  #pragma unroll
  for (int j = 0; j < 8; j++) ov[j] = f2bf(acc[j] * scale);
  *(uint4*)(agg + (size_t)node * HD + l16 * 8) = *(const uint4*)ov;
}

// ---------------- slim conv GEMM (agg precomputed; LDS-staged W) ----------------
template<int MODE>
__global__ void __launch_bounds__(256) k_conv(
    const int* __restrict__ flag, const ushort* __restrict__ h,
    const ushort* __restrict__ agg,
    const ushort* __restrict__ Wc, const float* __restrict__ vecs,
    void* __restrict__ outp){
  __shared__ __align__(16) ushort sW[16384];
  int f32 = flag[0];
  int tid  = threadIdx.x;
  int wave = tid >> 6;
  int lane = tid & 63;
  int quad = lane >> 4;
  int l16  = lane & 15;
  int rb  = blockIdx.x * 64 + wave * 16;

  int arow = rb + l16; if (arow >= N_NODES) arow = N_NODES - 1;
  const ushort* ab = agg + (size_t)arow * HD + quad * 8;
  const ushort* hb = h   + (size_t)arow * HD + quad * 8;
  bvec8 a[8];
  #pragma unroll
  for (int j = 0; j < 4; j++) a[j]     = *(const bvec8*)(ab + j * 32);
  #pragma unroll
  for (int j = 0; j < 4; j++) a[4 + j] = *(const bvec8*)(hb + j * 32);

  fvec4 acc[8];
  #pragma unroll
  for (int t = 0; t < 8; t++)
    #pragma unroll
    for (int i = 0; i < 4; i++) acc[t][i] = 0.f;

  #pragma unroll
  for (int s = 0; s < 2; s++){
    if (s) __syncthreads();
    #pragma unroll
    for (int it = 0; it < 8; it++){
      int off = it * 2048 + tid * 8;
      *(uint4*)(sW + off) = *(const uint4*)(Wc + s * 16384 + off);
    }
    __syncthreads();
    #pragma unroll
    for (int k0 = 0; k0 < 4; k0++){
      #pragma unroll
      for (int t = 0; t < 8; t++){
        bvec8 b = *(const bvec8*)(sW + ((k0 * 8 + t) * 64 + lane) * 8);
        acc[t] = __builtin_amdgcn_mfma_f32_16x16x32_bf16(a[s * 4 + k0], b, acc[t], 0, 0, 0);
      }
    }
  }

  if (MODE == 1){
    const float* bias   = vecs + 640;
    const float* gammav = vecs + 768;
    const float* betav  = vecs + 896;
    float zv[8][4];
    float s1[4] = {0.f, 0.f, 0.f, 0.f};
    float s2[4] = {0.f, 0.f, 0.f, 0.f};
    #pragma unroll
    for (int t = 0; t < 8; t++){
      float bc = bias[t * 16 + l16];
      #pragma unroll
      for (int i = 0; i < 4; i++){
        float v = acc[t][i] + bc;
        zv[t][i] = v;
        s1[i] += v;
        s2[i] += v * v;
      }
    }
    #pragma unroll
    for (int m = 1; m < 16; m <<= 1){
      #pragma unroll
      for (int i = 0; i < 4; i++){
        s1[i] += __shfl_xor(s1[i], m, 64);
        s2[i] += __shfl_xor(s2[i], m, 64);
      }
    }
    float mu[4], rsv[4];
    #pragma unroll
    for (int i = 0; i < 4; i++){
      mu[i] = s1[i] * (1.f / 128.f);
      float var = s2[i] * (1.f / 128.f) - mu[i] * mu[i];
      rsv[i] = rsqrtf(var + LN_EPS);
    }
    ushort* ob = (ushort*)outp;
    #pragma unroll
    for (int t = 0; t < 8; t++){
      int col = t * 16 + l16;
      float g = gammav[col], bt = betav[col];
      #pragma unroll
      for (int i = 0; i < 4; i++){
        int row = rb + quad * 4 + i;
        if (row >= N_NODES) continue;
        float v = (zv[t][i] - mu[i]) * rsv[i] * g + bt;
        v = fmaxf(v, 0.f);
        ob[(size_t)row * HD + col] = f2bf(v);
      }
    }
  } else {
    const float* bias = vecs + 1024;
    #pragma unroll
    for (int t = 0; t < 8; t++){
      int col = t * 16 + l16;
      float bc = bias[col];
      #pragma unroll
      for (int i = 0; i < 4; i++){
        int row = rb + quad * 4 + i;
        if (row >= N_NODES) continue;
        float v = acc[t][i] + bc;
        if (f32) ((float*)outp)[(size_t)row * HD + col] = v;
        else     ((ushort*)outp)[(size_t)row * HD + col] = f2bf(v);
      }
    }
  }
}

extern "C" void kernel_launch(void* const* d_in, const int* in_sizes, int n_in,
                              void* d_out, int out_size, void* d_ws, size_t ws_size,
                              hipStream_t stream) {
  const void* x          = d_in[0];
  const int*  ei         = (const int*)d_in[1];
  const int*  node_kind  = (const int*)d_in[2];
  const void* W_in       = d_in[3];
  const void* b_in       = d_in[4];
  const void* kind_embed = d_in[5];
  const void* ext_seed   = d_in[6];
  const void* Wl1        = d_in[7];
  const void* bl1        = d_in[8];
  const void* Wr1        = d_in[9];
  const void* gammap     = d_in[10];
  const void* betap      = d_in[11];
  const void* Wl2        = d_in[12];
  const void* bl2        = d_in[13];
  const void* Wr2        = d_in[14];
  const int* src = ei;
  const int* dst = ei + N_EDGES;

  char* ws = (char*)d_ws;
  size_t off = 0;
  auto alloc = [&](size_t bytes) -> void* {
    void* p = ws + off;
    off += (bytes + 255) & ~(size_t)255;
    return p;
  };
  int*    flag     = (int*)alloc(256);
  int*    total    = (int*)alloc(256);
  int*    cnt      = (int*)alloc(N_NODES * 4);
  int*    cursor   = (int*)alloc(N_NODES * 4);
  int*    rowstart = (int*)alloc(N_NODES * 4);
  int*    esrc     = (int*)alloc(N_EDGES * 4);
  ushort* WtA      = (ushort*)alloc(128 * 256 * 2);
  ushort* Wc1      = (ushort*)alloc(128 * 256 * 2);
  ushort* Wc2      = (ushort*)alloc(128 * 256 * 2);
  float*  vecs     = (float*)alloc(1152 * 4);
  ushort* h0       = (ushort*)alloc((size_t)N_NODES * HD * 2);
  ushort* h1       = (ushort*)alloc((size_t)N_NODES * HD * 2);
  ushort* aggb     = (ushort*)alloc((size_t)N_NODES * HD * 2);
  int*    echunk   = (int*)alloc(256);

  // ---- cooperative preprocessing (4 launches -> 1); fallback = round-5 path ----
  int use_coop = 0;
  {
    int dev = 0;
    (void)hipGetDevice(&dev);
    int attr = 0;
    if (hipDeviceGetAttribute(&attr, hipDeviceAttributeCooperativeLaunch, dev) == hipSuccess)
      use_coop = attr;
  }
  int grid = PRE_GRID;
  if (use_coop){
    int dev = 0; (void)hipGetDevice(&dev);
    int ncu = 256;
    (void)hipDeviceGetAttribute(&ncu, hipDeviceAttributeMultiprocessorCount, dev);
    int maxb = 0;
    if (hipOccupancyMaxActiveBlocksPerMultiprocessor(&maxb, (const void*)k_pre, 256, 0) == hipSuccess
        && maxb > 0){
      int cap = maxb * ncu;
      if (grid > cap) grid = cap;
    } else {
      use_coop = 0;
    }
    if (grid < 256) use_coop = 0;    // P2 assumes nthr >= N_NODES
  }
  int pre_done = 0;
  if (use_coop){
    const ushort* xus = (const ushort*)x;
    void* params[] = {
      (void*)&xus, (void*)&ei, (void*)&node_kind,
      (void*)&W_in, (void*)&b_in, (void*)&kind_embed, (void*)&ext_seed,
      (void*)&Wl1, (void*)&bl1, (void*)&Wr1,
      (void*)&gammap, (void*)&betap,
      (void*)&Wl2, (void*)&bl2, (void*)&Wr2,
      (void*)&flag, (void*)&total, (void*)&cnt, (void*)&cursor, (void*)&rowstart,
      (void*)&esrc, (void*)&WtA, (void*)&Wc1, (void*)&Wc2, (void*)&vecs,
      (void*)&h0, (void*)&echunk };
    hipError_t err = hipLaunchCooperativeKernel((const void*)k_pre, dim3(grid), dim3(256),
                                                params, 0, stream);
    pre_done = (err == hipSuccess);
  }
  if (!pre_done){
    k_zero<<<NODE_GRID, 256, 0, stream>>>(cnt, total);
    k_prep_count<<<128 + EDGE_GRID, 256, 0, stream>>>((const ushort*)x, flag, dst, cnt,
                                                      W_in, Wl1, Wr1, Wl2, Wr2, WtA, Wc1, Wc2,
                                                      b_in, kind_embed, ext_seed, bl1, gammap, betap, bl2, vecs);
    k_assign<<<NODE_GRID, 256, 0, stream>>>(cnt, rowstart, cursor, total);
    k_gemm_fill<<<GEMM_GRID + EDGE_GRID, 256, 0, stream>>>(flag, x, WtA, vecs, node_kind, h0,
                                                           src, dst, cursor, esrc);
  }

  int gath_grid = (N_NODES + 15) / 16;
  k_gather<<<gath_grid, 256, 0, stream>>>(h0, rowstart, cnt, esrc, aggb);
  k_conv<1><<<GEMM_GRID, 256, 0, stream>>>(flag, h0, aggb, Wc1, vecs, (void*)h1);
  k_gather<<<gath_grid, 256, 0, stream>>>(h1, rowstart, cnt, esrc, aggb);
  k_conv<2><<<GEMM_GRID, 256, 0, stream>>>(flag, h1, aggb, Wc2, vecs, d_out);
}

// Round 8
// 294.865 us; speedup vs baseline: 4.9875x; 1.5339x over previous
//
#include <hip/hip_runtime.h>
#include <stdint.h>

#define N_NODES 50000
#define N_EDGES 625000
#define DIN 256
#define HD 128
#define LN_EPS 1e-5f
#define AGG_STRIDE 136   // 128 + 8 halves pad (R0 fused-kernel layout)

#define GEMM_GRID 782      // (N_NODES+63)/64
#define EDGE_GRID 2442     // (N_EDGES+255)/256
#define NODE_GRID 196      // (N_NODES+255)/256
#define MIX_GRID 3224      // GEMM_GRID + EDGE_GRID, role-striped 1:3

typedef __attribute__((ext_vector_type(8))) short bvec8;
typedef __attribute__((ext_vector_type(4))) float fvec4;

__device__ inline float bf2f(ushort u){
  union { uint32_t u32; float f; } c; c.u32 = ((uint32_t)u) << 16; return c.f;
}
__device__ inline ushort f2bf(float f){
  union { float f; uint32_t u; } c; c.f = f;
  uint32_t u = c.u;
  return (ushort)((u + 0x7fffu + ((u >> 16) & 1u)) >> 16);
}
__device__ inline float rdany(const void* p, int i, int f32){
  return f32 ? ((const float*)p)[i] : bf2f(((const ushort*)p)[i]);
}

// ---------------- zero CSR state ----------------
__global__ void k_zero(int* __restrict__ cnt, int* __restrict__ total){
  int i = blockIdx.x * 256 + threadIdx.x;
  if (i < N_NODES) cnt[i] = 0;
  if (i == 0) total[0] = 0;
}

// ---------------- fused: weight prep (+inline dtype detect) || edge count ----------------
__global__ void k_prep_count(const ushort* __restrict__ x, int* __restrict__ flag,
                             const int* __restrict__ dst, int* __restrict__ cnt,
                             const void* __restrict__ W_in,
                             const void* __restrict__ Wl1, const void* __restrict__ Wr1,
                             const void* __restrict__ Wl2, const void* __restrict__ Wr2,
                             ushort* __restrict__ WtA, ushort* __restrict__ Wc1, ushort* __restrict__ Wc2,
                             const void* b_in, const void* kind_embed, const void* ext_seed,
                             const void* bl1, const void* gammap, const void* betap,
                             const void* bl2, float* __restrict__ vecs){
  if (blockIdx.x >= 128){
    int e = (blockIdx.x - 128) * 256 + threadIdx.x;
    if (e < N_EDGES) atomicAdd(&cnt[dst[e]], 1);
    return;
  }
  // inline dtype detect (same 4KB of x in every block; L2-hot)
  __shared__ int red[256];
  int t = threadIdx.x;
  {
    int c = 0;
    for (int j = 0; j < 8; j++){
      ushort u = x[t * 8 + j];
      int e = (u >> 7) & 0xff;
      if (e >= 0x88 || (e != 0 && e <= 0x70)) c++;
    }
    red[t] = c;
    __syncthreads();
    for (int off = 128; off > 0; off >>= 1){
      if (t < off) red[t] += red[t + off];
      __syncthreads();
    }
  }
  int f32 = (red[0] > 100) ? 1 : 0;
  if (blockIdx.x == 0 && t == 0) flag[0] = f32;

  int idx = blockIdx.x * 256 + t;
  {
    int c   = idx >> 9;
    int lam = (idx >> 3) & 63;
    int j   = idx & 7;
    int k0  = c >> 3;
    int tt  = c & 7;
    int n   = tt * 16 + (lam & 15);
    int k   = k0 * 32 + (lam >> 4) * 8 + j;
    WtA[idx] = f2bf(rdany(W_in, k * 128 + n, f32));
    if (k < 128){
      Wc1[idx] = f2bf(rdany(Wl1, k * 128 + n, f32));
      Wc2[idx] = f2bf(rdany(Wl2, k * 128 + n, f32));
    } else {
      Wc1[idx] = f2bf(rdany(Wr1, (k - 128) * 128 + n, f32));
      Wc2[idx] = f2bf(rdany(Wr2, (k - 128) * 128 + n, f32));
    }
  }
  if (blockIdx.x == 0){
    for (int i = t; i < 1152; i += 256){
      float v;
      if (i < 128)       v = rdany(b_in, i, f32);
      else if (i < 512)  v = rdany(kind_embed, i - 128, f32);
      else if (i < 640)  v = rdany(ext_seed, i - 512, f32);
      else if (i < 768)  v = rdany(bl1, i - 640, f32);
      else if (i < 896)  v = rdany(gammap, i - 768, f32);
      else if (i < 1024) v = rdany(betap, i - 896, f32);
      else               v = rdany(bl2, i - 1024, f32);
      vecs[i] = v;
    }
  }
}

// ---------------- CSR scan (also primes cursor = rowstart) ----------------
__global__ void k_assign(const int* __restrict__ cnt, int* __restrict__ rowstart,
                         int* __restrict__ cursor, int* __restrict__ total){
  int i = blockIdx.x * 256 + threadIdx.x;
  int lane = threadIdx.x & 63;
  int c = (i < N_NODES) ? cnt[i] : 0;
  int scan = c;
  #pragma unroll
  for (int m = 1; m < 64; m <<= 1){
    int v = __shfl_up(scan, m, 64);
    if (lane >= m) scan += v;
  }
  int wave_total = __shfl(scan, 63, 64);
  int base = 0;
  if (lane == 63) base = atomicAdd(total, wave_total);
  base = __shfl(base, 63, 64);
  if (i < N_NODES){
    int rsv = base + scan - c;
    rowstart[i] = rsv;
    cursor[i]   = rsv;    // fill's atomicAdd lands directly on the esrc slot
  }
}

// ---------------- fused: input GEMM || CSR fill — ROLE-STRIPED ----------------
// Roles interleaved 1 gemm : 3 fill so both populations are co-resident on
// every CU from t=0 — fill's random-atomic latency hides under gemm's
// MFMA/LDS work (previous block-ordered layout ran them back-to-back).
__global__ void __launch_bounds__(256) k_gemm_fill(
    const int* __restrict__ flag, const void* __restrict__ xin,
    const ushort* __restrict__ WtA, const float* __restrict__ vecs,
    const int* __restrict__ node_kind, ushort* __restrict__ h0,
    const int* __restrict__ src, const int* __restrict__ dst,
    int* __restrict__ cursor, int* __restrict__ esrc){
  __shared__ __align__(16) ushort sW[16384];   // 32 KB (half of WtA at a time)
  int bid = blockIdx.x;
  int is_gemm = 0, widx = 0;
  if (bid < GEMM_GRID * 4){
    if ((bid & 3) == 0){ is_gemm = 1; widx = bid >> 2; }
    else               { widx = bid - (bid >> 2) - 1; }     // fill idx among first stripes
  } else {
    widx = (GEMM_GRID * 3) + (bid - GEMM_GRID * 4);          // tail: all fill
  }
  if (!is_gemm){
    int e = widx * 256 + threadIdx.x;
    if (e < N_EDGES){
      int d = dst[e];
      int pos = atomicAdd(&cursor[d], 1);
      esrc[pos] = src[e];
    }
    return;
  }
  int f32 = flag[0];
  int tid  = threadIdx.x;
  int wave = tid >> 6;
  int lane = tid & 63;
  int quad = lane >> 4;
  int l16  = lane & 15;
  int rb = widx * 64 + wave * 16;

  fvec4 acc[8];
  #pragma unroll
  for (int t = 0; t < 8; t++)
    #pragma unroll
    for (int i = 0; i < 4; i++) acc[t][i] = 0.f;

  int arow = rb + l16; if (arow >= N_NODES) arow = N_NODES - 1;
  const ushort* abf = (const ushort*)xin + (size_t)arow * DIN + quad * 8;
  const float*  af  = (const float*)xin + (size_t)arow * DIN + quad * 8;

  bvec8 a[8];
  if (f32){
    #pragma unroll
    for (int k0 = 0; k0 < 8; k0++){
      fvec4 lo = *(const fvec4*)(af + k0 * 32);
      fvec4 hi = *(const fvec4*)(af + k0 * 32 + 4);
      a[k0][0] = (short)f2bf(lo[0]); a[k0][1] = (short)f2bf(lo[1]);
      a[k0][2] = (short)f2bf(lo[2]); a[k0][3] = (short)f2bf(lo[3]);
      a[k0][4] = (short)f2bf(hi[0]); a[k0][5] = (short)f2bf(hi[1]);
      a[k0][6] = (short)f2bf(hi[2]); a[k0][7] = (short)f2bf(hi[3]);
    }
  } else {
    #pragma unroll
    for (int k0 = 0; k0 < 8; k0++) a[k0] = *(const bvec8*)(abf + k0 * 32);
  }

  #pragma unroll
  for (int s = 0; s < 2; s++){
    if (s) __syncthreads();
    #pragma unroll
    for (int it = 0; it < 8; it++){
      int off = it * 2048 + tid * 8;
      *(uint4*)(sW + off) = *(const uint4*)(WtA + s * 16384 + off);
    }
    __syncthreads();
    #pragma unroll
    for (int k0 = 0; k0 < 4; k0++){
      #pragma unroll
      for (int t = 0; t < 8; t++){
        bvec8 b = *(const bvec8*)(sW + ((k0 * 8 + t) * 64 + lane) * 8);
        acc[t] = __builtin_amdgcn_mfma_f32_16x16x32_bf16(a[s * 4 + k0], b, acc[t], 0, 0, 0);
      }
    }
  }

  const float* b_in  = vecs;
  const float* kinde = vecs + 128;
  const float* ext   = vecs + 512;
  #pragma unroll
  for (int i = 0; i < 4; i++){
    int row = rb + quad * 4 + i;
    if (row >= N_NODES) continue;
    int kind = node_kind[row];
    float extf = (kind != 0) ? 1.f : 0.f;
    #pragma unroll
    for (int t = 0; t < 8; t++){
      int col = t * 16 + l16;
      float v = acc[t][i] + b_in[col] + kinde[kind * HD + col] + extf * ext[col];
      h0[(size_t)row * HD + col] = f2bf(v);
    }
  }
}

// ---------------- fused gather + conv GEMM (round-0 kernel, proven 45us) ----------------
template<int MODE>
__global__ void __launch_bounds__(256) k_conv_fused(
    const int* __restrict__ flag, const ushort* __restrict__ h,
    const int* __restrict__ rowstart, const int* __restrict__ cnt,
    const int* __restrict__ esrc,
    const ushort* __restrict__ Wc, const float* __restrict__ vecs,
    void* __restrict__ outp){
  __shared__ __align__(16) ushort sbuf[16384];   // 32 KB: agg(8704) then weights(16384)
  int f32 = flag[0];
  int tid  = threadIdx.x;
  int wave = tid >> 6;
  int lane = tid & 63;
  int quad = lane >> 4;
  int l16  = lane & 15;
  int rb0 = blockIdx.x * 64;
  int rb  = rb0 + wave * 16;

  // self-row (h-half) A-frags: issue global loads early
  int arow = rb + l16; if (arow >= N_NODES) arow = N_NODES - 1;
  const ushort* hb = h + (size_t)arow * HD + quad * 8;
  bvec8 a[8];
  #pragma unroll
  for (int j = 0; j < 4; j++) a[4 + j] = *(const bvec8*)(hb + j * 32);

  // ---- phase 1: gather agg rows into LDS ----
  int eg = quad;  // node selector within round
  #pragma unroll
  for (int r = 0; r < 4; r++){
    int nd = wave * 16 + r * 4 + eg;     // node within block (0..63)
    int n  = rb0 + nd;
    bool valid = n < N_NODES;
    int b   = valid ? rowstart[n] : 0;
    int deg = valid ? cnt[n] : 0;
    int e   = b + deg;
    float acc[8];
    #pragma unroll
    for (int j = 0; j < 8; j++) acc[j] = 0.f;
    for (int i = b; i < e; i += 4){
      int i1 = i + 1, i2 = i + 2, i3 = i + 3;
      bool v1 = i1 < e, v2 = i2 < e, v3 = i3 < e;
      int s0 = esrc[i];
      int s1 = esrc[v1 ? i1 : i];
      int s2 = esrc[v2 ? i2 : i];
      int s3 = esrc[v3 ? i3 : i];
      uint4 p0 = *(const uint4*)(h + (size_t)s0 * HD + l16 * 8);
      uint4 p1 = {0,0,0,0}, p2 = {0,0,0,0}, p3 = {0,0,0,0};
      if (v1) p1 = *(const uint4*)(h + (size_t)s1 * HD + l16 * 8);
      if (v2) p2 = *(const uint4*)(h + (size_t)s2 * HD + l16 * 8);
      if (v3) p3 = *(const uint4*)(h + (size_t)s3 * HD + l16 * 8);
      const uint32_t* w0 = (const uint32_t*)&p0;
      const uint32_t* w1 = (const uint32_t*)&p1;
      const uint32_t* w2 = (const uint32_t*)&p2;
      const uint32_t* w3 = (const uint32_t*)&p3;
      #pragma unroll
      for (int j = 0; j < 4; j++){
        acc[2*j]   += bf2f((ushort)(w0[j] & 0xffffu)) + bf2f((ushort)(w1[j] & 0xffffu))
                    + bf2f((ushort)(w2[j] & 0xffffu)) + bf2f((ushort)(w3[j] & 0xffffu));
        acc[2*j+1] += bf2f((ushort)(w0[j] >> 16)) + bf2f((ushort)(w1[j] >> 16))
                    + bf2f((ushort)(w2[j] >> 16)) + bf2f((ushort)(w3[j] >> 16));
      }
    }
    float scale = (deg > 0) ? 1.f / (float)deg : 0.f;
    ushort* dstp = sbuf + nd * AGG_STRIDE + l16 * 8;
    #pragma unroll
    for (int j = 0; j < 8; j++) dstp[j] = f2bf(acc[j] * scale);
  }
  __syncthreads();

  // ---- A-frags (agg half) from LDS ----
  {
    int nd = wave * 16 + l16;
    const ushort* ap = sbuf + nd * AGG_STRIDE + quad * 8;
    #pragma unroll
    for (int j = 0; j < 4; j++) a[j] = *(const bvec8*)(ap + j * 32);
  }
  __syncthreads();   // everyone done reading agg before overwrite

  fvec4 acc[8];
  #pragma unroll
  for (int t = 0; t < 8; t++)
    #pragma unroll
    for (int i = 0; i < 4; i++) acc[t][i] = 0.f;

  // ---- weights in two 32KB half-stages over the same LDS ----
  #pragma unroll
  for (int s = 0; s < 2; s++){
    #pragma unroll
    for (int it = 0; it < 8; it++){
      int off = it * 2048 + tid * 8;
      *(uint4*)(sbuf + off) = *(const uint4*)(Wc + s * 16384 + off);
    }
    __syncthreads();
    #pragma unroll
    for (int k0 = 0; k0 < 4; k0++){
      #pragma unroll
      for (int t = 0; t < 8; t++){
        bvec8 b = *(const bvec8*)(sbuf + ((k0 * 8 + t) * 64 + lane) * 8);
        acc[t] = __builtin_amdgcn_mfma_f32_16x16x32_bf16(a[s * 4 + k0], b, acc[t], 0, 0, 0);
      }
    }
    __syncthreads();
  }

  if (MODE == 1){
    const float* bias   = vecs + 640;
    const float* gammav = vecs + 768;
    const float* betav  = vecs + 896;
    float zv[8][4];
    float s1[4] = {0.f, 0.f, 0.f, 0.f};
    float s2[4] = {0.f, 0.f, 0.f, 0.f};
    #pragma unroll
    for (int t = 0; t < 8; t++){
      float bc = bias[t * 16 + l16];
      #pragma unroll
      for (int i = 0; i < 4; i++){
        float v = acc[t][i] + bc;
        zv[t][i] = v;
        s1[i] += v;
        s2[i] += v * v;
      }
    }
    #pragma unroll
    for (int m = 1; m < 16; m <<= 1){
      #pragma unroll
      for (int i = 0; i < 4; i++){
        s1[i] += __shfl_xor(s1[i], m, 64);
        s2[i] += __shfl_xor(s2[i], m, 64);
      }
    }
    float mu[4], rs[4];
    #pragma unroll
    for (int i = 0; i < 4; i++){
      mu[i] = s1[i] * (1.f / 128.f);
      float var = s2[i] * (1.f / 128.f) - mu[i] * mu[i];
      rs[i] = rsqrtf(var + LN_EPS);
    }
    ushort* ob = (ushort*)outp;
    #pragma unroll
    for (int t = 0; t < 8; t++){
      int col = t * 16 + l16;
      float g = gammav[col], bt = betav[col];
      #pragma unroll
      for (int i = 0; i < 4; i++){
        int row = rb + quad * 4 + i;
        if (row >= N_NODES) continue;
        float v = (zv[t][i] - mu[i]) * rs[i] * g + bt;
        v = fmaxf(v, 0.f);
        ob[(size_t)row * HD + col] = f2bf(v);
      }
    }
  } else {
    const float* bias = vecs + 1024;
    #pragma unroll
    for (int t = 0; t < 8; t++){
      int col = t * 16 + l16;
      float bc = bias[col];
      #pragma unroll
      for (int i = 0; i < 4; i++){
        int row = rb + quad * 4 + i;
        if (row >= N_NODES) continue;
        float v = acc[t][i] + bc;
        if (f32) ((float*)outp)[(size_t)row * HD + col] = v;
        else     ((ushort*)outp)[(size_t)row * HD + col] = f2bf(v);
      }
    }
  }
}

extern "C" void kernel_launch(void* const* d_in, const int* in_sizes, int n_in,
                              void* d_out, int out_size, void* d_ws, size_t ws_size,
                              hipStream_t stream) {
  const void* x          = d_in[0];
  const int*  ei         = (const int*)d_in[1];
  const int*  node_kind  = (const int*)d_in[2];
  const void* W_in       = d_in[3];
  const void* b_in       = d_in[4];
  const void* kind_embed = d_in[5];
  const void* ext_seed   = d_in[6];
  const void* Wl1        = d_in[7];
  const void* bl1        = d_in[8];
  const void* Wr1        = d_in[9];
  const void* gammap     = d_in[10];
  const void* betap      = d_in[11];
  const void* Wl2        = d_in[12];
  const void* bl2        = d_in[13];
  const void* Wr2        = d_in[14];
  const int* src = ei;
  const int* dst = ei + N_EDGES;

  char* ws = (char*)d_ws;
  size_t off = 0;
  auto alloc = [&](size_t bytes) -> void* {
    void* p = ws + off;
    off += (bytes + 255) & ~(size_t)255;
    return p;
  };
  int*    flag     = (int*)alloc(256);
  int*    total    = (int*)alloc(256);
  int*    cnt      = (int*)alloc(N_NODES * 4);
  int*    cursor   = (int*)alloc(N_NODES * 4);
  int*    rowstart = (int*)alloc(N_NODES * 4);
  int*    esrc     = (int*)alloc(N_EDGES * 4);
  ushort* WtA      = (ushort*)alloc(128 * 256 * 2);
  ushort* Wc1      = (ushort*)alloc(128 * 256 * 2);
  ushort* Wc2      = (ushort*)alloc(128 * 256 * 2);
  float*  vecs     = (float*)alloc(1152 * 4);
  ushort* h0       = (ushort*)alloc((size_t)N_NODES * HD * 2);
  ushort* h1       = (ushort*)alloc((size_t)N_NODES * HD * 2);

  k_zero<<<NODE_GRID, 256, 0, stream>>>(cnt, total);
  k_prep_count<<<128 + EDGE_GRID, 256, 0, stream>>>((const ushort*)x, flag, dst, cnt,
                                                    W_in, Wl1, Wr1, Wl2, Wr2, WtA, Wc1, Wc2,
                                                    b_in, kind_embed, ext_seed, bl1, gammap, betap, bl2, vecs);
  k_assign<<<NODE_GRID, 256, 0, stream>>>(cnt, rowstart, cursor, total);
  k_gemm_fill<<<MIX_GRID, 256, 0, stream>>>(flag, x, WtA, vecs, node_kind, h0,
                                            src, dst, cursor, esrc);
  k_conv_fused<1><<<GEMM_GRID, 256, 0, stream>>>(flag, h0, rowstart, cnt, esrc, Wc1, vecs, (void*)h1);
  k_conv_fused<2><<<GEMM_GRID, 256, 0, stream>>>(flag, h1, rowstart, cnt, esrc, Wc2, vecs, d_out);
}

// Round 9
// 275.383 us; speedup vs baseline: 5.3403x; 1.0707x over previous
//
#include <hip/hip_runtime.h>
#include <stdint.h>

#define N_NODES 50000
#define N_EDGES 625000
#define DIN 256
#define HD 128
#define LN_EPS 1e-5f

#define GEMM_GRID 782      // (N_NODES+63)/64
#define EDGE_GRID 2442     // (N_EDGES+255)/256
#define NODE_GRID 196      // (N_NODES+255)/256

typedef __attribute__((ext_vector_type(8))) short bvec8;
typedef __attribute__((ext_vector_type(4))) float fvec4;

__device__ inline float bf2f(ushort u){
  union { uint32_t u32; float f; } c; c.u32 = ((uint32_t)u) << 16; return c.f;
}
__device__ inline ushort f2bf(float f){
  union { float f; uint32_t u; } c; c.f = f;
  uint32_t u = c.u;
  return (ushort)((u + 0x7fffu + ((u >> 16) & 1u)) >> 16);
}
__device__ inline float rdany(const void* p, int i, int f32){
  return f32 ? ((const float*)p)[i] : bf2f(((const ushort*)p)[i]);
}

// ---------------- zero CSR state (cursor init'd in k_assign) ----------------
__global__ void k_zero(int* __restrict__ cnt, int* __restrict__ total){
  int i = blockIdx.x * 256 + threadIdx.x;
  if (i < N_NODES) cnt[i] = 0;
  if (i == 0) total[0] = 0;
}

// ---------------- fused: weight prep (+inline dtype detect) || edge count ----------------
__global__ void k_prep_count(const ushort* __restrict__ x, int* __restrict__ flag,
                             const int* __restrict__ dst, int* __restrict__ cnt,
                             const void* __restrict__ W_in,
                             const void* __restrict__ Wl1, const void* __restrict__ Wr1,
                             const void* __restrict__ Wl2, const void* __restrict__ Wr2,
                             ushort* __restrict__ WtA, ushort* __restrict__ Wc1, ushort* __restrict__ Wc2,
                             const void* b_in, const void* kind_embed, const void* ext_seed,
                             const void* bl1, const void* gammap, const void* betap,
                             const void* bl2, float* __restrict__ vecs){
  if (blockIdx.x >= 128){
    int e = (blockIdx.x - 128) * 256 + threadIdx.x;
    if (e < N_EDGES) atomicAdd(&cnt[dst[e]], 1);
    return;
  }
  // inline dtype detect (same 4KB of x in every block; L2-hot)
  __shared__ int red[256];
  int t = threadIdx.x;
  {
    int c = 0;
    for (int j = 0; j < 8; j++){
      ushort u = x[t * 8 + j];
      int e = (u >> 7) & 0xff;
      if (e >= 0x88 || (e != 0 && e <= 0x70)) c++;
    }
    red[t] = c;
    __syncthreads();
    for (int off = 128; off > 0; off >>= 1){
      if (t < off) red[t] += red[t + off];
      __syncthreads();
    }
  }
  int f32 = (red[0] > 100) ? 1 : 0;
  if (blockIdx.x == 0 && t == 0) flag[0] = f32;

  int idx = blockIdx.x * 256 + t;
  {
    int c   = idx >> 9;
    int lam = (idx >> 3) & 63;
    int j   = idx & 7;
    int k0  = c >> 3;
    int tt  = c & 7;
    int n   = tt * 16 + (lam & 15);
    int k   = k0 * 32 + (lam >> 4) * 8 + j;
    WtA[idx] = f2bf(rdany(W_in, k * 128 + n, f32));
    if (k < 128){
      Wc1[idx] = f2bf(rdany(Wl1, k * 128 + n, f32));
      Wc2[idx] = f2bf(rdany(Wl2, k * 128 + n, f32));
    } else {
      Wc1[idx] = f2bf(rdany(Wr1, (k - 128) * 128 + n, f32));
      Wc2[idx] = f2bf(rdany(Wr2, (k - 128) * 128 + n, f32));
    }
  }
  if (blockIdx.x == 0){
    for (int i = t; i < 1152; i += 256){
      float v;
      if (i < 128)       v = rdany(b_in, i, f32);
      else if (i < 512)  v = rdany(kind_embed, i - 128, f32);
      else if (i < 640)  v = rdany(ext_seed, i - 512, f32);
      else if (i < 768)  v = rdany(bl1, i - 640, f32);
      else if (i < 896)  v = rdany(gammap, i - 768, f32);
      else if (i < 1024) v = rdany(betap, i - 896, f32);
      else               v = rdany(bl2, i - 1024, f32);
      vecs[i] = v;
    }
  }
}

// ---------------- CSR scan (also primes cursor = rowstart) ----------------
__global__ void k_assign(const int* __restrict__ cnt, int* __restrict__ rowstart,
                         int* __restrict__ cursor, int* __restrict__ total){
  int i = blockIdx.x * 256 + threadIdx.x;
  int lane = threadIdx.x & 63;
  int c = (i < N_NODES) ? cnt[i] : 0;
  int scan = c;
  #pragma unroll
  for (int m = 1; m < 64; m <<= 1){
    int v = __shfl_up(scan, m, 64);
    if (lane >= m) scan += v;
  }
  int wave_total = __shfl(scan, 63, 64);
  int base = 0;
  if (lane == 63) base = atomicAdd(total, wave_total);
  base = __shfl(base, 63, 64);
  if (i < N_NODES){
    int rsv = base + scan - c;
    rowstart[i] = rsv;
    cursor[i]   = rsv;    // fill's atomicAdd lands directly on the esrc slot
  }
}

// ---------------- fused: CSR fill (FIRST) || input GEMM ----------------
// Fill blocks dispatched first: short, homogeneous, saturate all CUs at the
// LDS cap immediately and drain in ~15us; the grid-limited gemm cohort
// backfills and its latency tail overlaps the fill drain. (Gemm-first
// measured 57.6us; striped 70.5us — ordering matters on this dispatcher.)
__global__ void __launch_bounds__(256) k_gemm_fill(
    const int* __restrict__ flag, const void* __restrict__ xin,
    const ushort* __restrict__ WtA, const float* __restrict__ vecs,
    const int* __restrict__ node_kind, ushort* __restrict__ h0,
    const int* __restrict__ src, const int* __restrict__ dst,
    int* __restrict__ cursor, int* __restrict__ esrc){
  __shared__ __align__(16) ushort sW[16384];   // 32 KB (half of WtA at a time)
  if (blockIdx.x < EDGE_GRID){
    int e = blockIdx.x * 256 + threadIdx.x;
    if (e < N_EDGES){
      int d = dst[e];
      int pos = atomicAdd(&cursor[d], 1);
      esrc[pos] = src[e];
    }
    return;
  }
  int f32 = flag[0];
  int tid  = threadIdx.x;
  int wave = tid >> 6;
  int lane = tid & 63;
  int quad = lane >> 4;
  int l16  = lane & 15;
  int rb = (blockIdx.x - EDGE_GRID) * 64 + wave * 16;

  fvec4 acc[8];
  #pragma unroll
  for (int t = 0; t < 8; t++)
    #pragma unroll
    for (int i = 0; i < 4; i++) acc[t][i] = 0.f;

  int arow = rb + l16; if (arow >= N_NODES) arow = N_NODES - 1;
  const ushort* abf = (const ushort*)xin + (size_t)arow * DIN + quad * 8;
  const float*  af  = (const float*)xin + (size_t)arow * DIN + quad * 8;

  bvec8 a[8];
  if (f32){
    #pragma unroll
    for (int k0 = 0; k0 < 8; k0++){
      fvec4 lo = *(const fvec4*)(af + k0 * 32);
      fvec4 hi = *(const fvec4*)(af + k0 * 32 + 4);
      a[k0][0] = (short)f2bf(lo[0]); a[k0][1] = (short)f2bf(lo[1]);
      a[k0][2] = (short)f2bf(lo[2]); a[k0][3] = (short)f2bf(lo[3]);
      a[k0][4] = (short)f2bf(hi[0]); a[k0][5] = (short)f2bf(hi[1]);
      a[k0][6] = (short)f2bf(hi[2]); a[k0][7] = (short)f2bf(hi[3]);
    }
  } else {
    #pragma unroll
    for (int k0 = 0; k0 < 8; k0++) a[k0] = *(const bvec8*)(abf + k0 * 32);
  }

  #pragma unroll
  for (int s = 0; s < 2; s++){
    if (s) __syncthreads();
    #pragma unroll
    for (int it = 0; it < 8; it++){
      int off = it * 2048 + tid * 8;
      *(uint4*)(sW + off) = *(const uint4*)(WtA + s * 16384 + off);
    }
    __syncthreads();
    #pragma unroll
    for (int k0 = 0; k0 < 4; k0++){
      #pragma unroll
      for (int t = 0; t < 8; t++){
        bvec8 b = *(const bvec8*)(sW + ((k0 * 8 + t) * 64 + lane) * 8);
        acc[t] = __builtin_amdgcn_mfma_f32_16x16x32_bf16(a[s * 4 + k0], b, acc[t], 0, 0, 0);
      }
    }
  }

  const float* b_in  = vecs;
  const float* kinde = vecs + 128;
  const float* ext   = vecs + 512;
  #pragma unroll
  for (int i = 0; i < 4; i++){
    int row = rb + quad * 4 + i;
    if (row >= N_NODES) continue;
    int kind = node_kind[row];
    float extf = (kind != 0) ? 1.f : 0.f;
    #pragma unroll
    for (int t = 0; t < 8; t++){
      int col = t * 16 + l16;
      float v = acc[t][i] + b_in[col] + kinde[kind * HD + col] + extf * ext[col];
      h0[(size_t)row * HD + col] = f2bf(v);
    }
  }
}

// ---------------- standalone gather: one 16-lane quad per node ----------------
// 8 rows in flight per lane (proven config), f32 register accumulate,
// one coalesced 16B bf16 store of the scaled mean (h-layout, frag-ready).
__global__ void __launch_bounds__(256) k_gather(
    const ushort* __restrict__ h, const int* __restrict__ rowstart,
    const int* __restrict__ cnt, const int* __restrict__ esrc,
    ushort* __restrict__ agg){
  int tid  = threadIdx.x;
  int node = blockIdx.x * 16 + (tid >> 4);
  int l16  = tid & 15;
  if (node >= N_NODES) return;
  int b   = rowstart[node];
  int deg = cnt[node];
  int e   = b + deg;
  float acc[8];
  #pragma unroll
  for (int j = 0; j < 8; j++) acc[j] = 0.f;
  for (int i = b; i < e; i += 8){
    int idx[8];
    #pragma unroll
    for (int k = 0; k < 8; k++){
      int ee = i + k;
      idx[k] = esrc[ee < e ? ee : e - 1];
    }
    uint4 r[8];
    #pragma unroll
    for (int k = 0; k < 8; k++)
      r[k] = *(const uint4*)(h + (size_t)idx[k] * HD + l16 * 8);
    #pragma unroll
    for (int k = 0; k < 8; k++){
      if (i + k < e){
        const uint32_t* w = (const uint32_t*)&r[k];
        #pragma unroll
        for (int j = 0; j < 4; j++){
          acc[2*j]   += bf2f((ushort)(w[j] & 0xffffu));
          acc[2*j+1] += bf2f((ushort)(w[j] >> 16));
        }
      }
    }
  }
  float scale = (deg > 0) ? 1.f / (float)deg : 0.f;
  ushort ov[8];
  #pragma unroll
  for (int j = 0; j < 8; j++) ov[j] = f2bf(acc[j] * scale);
  *(uint4*)(agg + (size_t)node * HD + l16 * 8) = *(const uint4*)ov;
}

// ---------------- slim conv GEMM (agg precomputed; LDS-staged W) ----------------
template<int MODE>
__global__ void __launch_bounds__(256) k_conv(
    const int* __restrict__ flag, const ushort* __restrict__ h,
    const ushort* __restrict__ agg,
    const ushort* __restrict__ Wc, const float* __restrict__ vecs,
    void* __restrict__ outp){
  __shared__ __align__(16) ushort sW[16384];   // 32 KB
  int f32 = flag[0];
  int tid  = threadIdx.x;
  int wave = tid >> 6;
  int lane = tid & 63;
  int quad = lane >> 4;
  int l16  = lane & 15;
  int rb  = blockIdx.x * 64 + wave * 16;

  int arow = rb + l16; if (arow >= N_NODES) arow = N_NODES - 1;
  const ushort* ab = agg + (size_t)arow * HD + quad * 8;
  const ushort* hb = h   + (size_t)arow * HD + quad * 8;
  bvec8 a[8];
  #pragma unroll
  for (int j = 0; j < 4; j++) a[j]     = *(const bvec8*)(ab + j * 32);
  #pragma unroll
  for (int j = 0; j < 4; j++) a[4 + j] = *(const bvec8*)(hb + j * 32);

  fvec4 acc[8];
  #pragma unroll
  for (int t = 0; t < 8; t++)
    #pragma unroll
    for (int i = 0; i < 4; i++) acc[t][i] = 0.f;

  #pragma unroll
  for (int s = 0; s < 2; s++){
    if (s) __syncthreads();
    #pragma unroll
    for (int it = 0; it < 8; it++){
      int off = it * 2048 + tid * 8;
      *(uint4*)(sW + off) = *(const uint4*)(Wc + s * 16384 + off);
    }
    __syncthreads();
    #pragma unroll
    for (int k0 = 0; k0 < 4; k0++){
      #pragma unroll
      for (int t = 0; t < 8; t++){
        bvec8 b = *(const bvec8*)(sW + ((k0 * 8 + t) * 64 + lane) * 8);
        acc[t] = __builtin_amdgcn_mfma_f32_16x16x32_bf16(a[s * 4 + k0], b, acc[t], 0, 0, 0);
      }
    }
  }

  if (MODE == 1){
    const float* bias   = vecs + 640;
    const float* gammav = vecs + 768;
    const float* betav  = vecs + 896;
    float zv[8][4];
    float s1[4] = {0.f, 0.f, 0.f, 0.f};
    float s2[4] = {0.f, 0.f, 0.f, 0.f};
    #pragma unroll
    for (int t = 0; t < 8; t++){
      float bc = bias[t * 16 + l16];
      #pragma unroll
      for (int i = 0; i < 4; i++){
        float v = acc[t][i] + bc;
        zv[t][i] = v;
        s1[i] += v;
        s2[i] += v * v;
      }
    }
    #pragma unroll
    for (int m = 1; m < 16; m <<= 1){
      #pragma unroll
      for (int i = 0; i < 4; i++){
        s1[i] += __shfl_xor(s1[i], m, 64);
        s2[i] += __shfl_xor(s2[i], m, 64);
      }
    }
    float mu[4], rsv[4];
    #pragma unroll
    for (int i = 0; i < 4; i++){
      mu[i] = s1[i] * (1.f / 128.f);
      float var = s2[i] * (1.f / 128.f) - mu[i] * mu[i];
      rsv[i] = rsqrtf(var + LN_EPS);
    }
    ushort* ob = (ushort*)outp;
    #pragma unroll
    for (int t = 0; t < 8; t++){
      int col = t * 16 + l16;
      float g = gammav[col], bt = betav[col];
      #pragma unroll
      for (int i = 0; i < 4; i++){
        int row = rb + quad * 4 + i;
        if (row >= N_NODES) continue;
        float v = (zv[t][i] - mu[i]) * rsv[i] * g + bt;
        v = fmaxf(v, 0.f);
        ob[(size_t)row * HD + col] = f2bf(v);
      }
    }
  } else {
    const float* bias = vecs + 1024;
    #pragma unroll
    for (int t = 0; t < 8; t++){
      int col = t * 16 + l16;
      float bc = bias[col];
      #pragma unroll
      for (int i = 0; i < 4; i++){
        int row = rb + quad * 4 + i;
        if (row >= N_NODES) continue;
        float v = acc[t][i] + bc;
        if (f32) ((float*)outp)[(size_t)row * HD + col] = v;
        else     ((ushort*)outp)[(size_t)row * HD + col] = f2bf(v);
      }
    }
  }
}

extern "C" void kernel_launch(void* const* d_in, const int* in_sizes, int n_in,
                              void* d_out, int out_size, void* d_ws, size_t ws_size,
                              hipStream_t stream) {
  const void* x          = d_in[0];
  const int*  ei         = (const int*)d_in[1];
  const int*  node_kind  = (const int*)d_in[2];
  const void* W_in       = d_in[3];
  const void* b_in       = d_in[4];
  const void* kind_embed = d_in[5];
  const void* ext_seed   = d_in[6];
  const void* Wl1        = d_in[7];
  const void* bl1        = d_in[8];
  const void* Wr1        = d_in[9];
  const void* gammap     = d_in[10];
  const void* betap      = d_in[11];
  const void* Wl2        = d_in[12];
  const void* bl2        = d_in[13];
  const void* Wr2        = d_in[14];
  const int* src = ei;
  const int* dst = ei + N_EDGES;

  char* ws = (char*)d_ws;
  size_t off = 0;
  auto alloc = [&](size_t bytes) -> void* {
    void* p = ws + off;
    off += (bytes + 255) & ~(size_t)255;
    return p;
  };
  int*    flag     = (int*)alloc(256);
  int*    total    = (int*)alloc(256);
  int*    cnt      = (int*)alloc(N_NODES * 4);
  int*    cursor   = (int*)alloc(N_NODES * 4);
  int*    rowstart = (int*)alloc(N_NODES * 4);
  int*    esrc     = (int*)alloc(N_EDGES * 4);
  ushort* WtA      = (ushort*)alloc(128 * 256 * 2);
  ushort* Wc1      = (ushort*)alloc(128 * 256 * 2);
  ushort* Wc2      = (ushort*)alloc(128 * 256 * 2);
  float*  vecs     = (float*)alloc(1152 * 4);
  ushort* h0       = (ushort*)alloc((size_t)N_NODES * HD * 2);
  ushort* h1       = (ushort*)alloc((size_t)N_NODES * HD * 2);
  ushort* aggb     = (ushort*)alloc((size_t)N_NODES * HD * 2);

  k_zero<<<NODE_GRID, 256, 0, stream>>>(cnt, total);
  k_prep_count<<<128 + EDGE_GRID, 256, 0, stream>>>((const ushort*)x, flag, dst, cnt,
                                                    W_in, Wl1, Wr1, Wl2, Wr2, WtA, Wc1, Wc2,
                                                    b_in, kind_embed, ext_seed, bl1, gammap, betap, bl2, vecs);
  k_assign<<<NODE_GRID, 256, 0, stream>>>(cnt, rowstart, cursor, total);
  k_gemm_fill<<<EDGE_GRID + GEMM_GRID, 256, 0, stream>>>(flag, x, WtA, vecs, node_kind, h0,
                                                         src, dst, cursor, esrc);

  int gath_grid = (N_NODES + 15) / 16;
  k_gather<<<gath_grid, 256, 0, stream>>>(h0, rowstart, cnt, esrc, aggb);
  k_conv<1><<<GEMM_GRID, 256, 0, stream>>>(flag, h0, aggb, Wc1, vecs, (void*)h1);
  k_gather<<<gath_grid, 256, 0, stream>>>(h1, rowstart, cnt, esrc, aggb);
  k_conv<2><<<GEMM_GRID, 256, 0, stream>>>(flag, h1, aggb, Wc2, vecs, d_out);
}